// Round 7
// baseline (1469.950 us; speedup 1.0000x reference)
//
#include <hip/hip_runtime.h>
#include <hip/hip_fp16.h>
#include <math.h>
#include <cstdint>

#define N_NODES 50000
#define F_IN    128
#define HIDDEN  256
#define NHEAD   4
#define HEADD   64
#define NEDGE   400000
#define NTYPE   2
#define SNB     256   // stats partial-reduction blocks per type

typedef unsigned short u16;
typedef float f32x4 __attribute__((ext_vector_type(4)));
typedef short s16x8 __attribute__((ext_vector_type(8)));

__device__ __forceinline__ float lrelu(float x) { return x > 0.f ? x : 0.2f * x; }

__device__ __forceinline__ void bsplit(float f, u16& hi, u16& lo) {
  unsigned u = __float_as_uint(f);
  hi = (u16)(u >> 16);
  float r = f - __uint_as_float(u & 0xffff0000u);
  lo = (u16)(__float_as_uint(r) >> 16);
}

__device__ __forceinline__ u16 f2h(float f) {
  return __half_as_ushort(__float2half(f));
}

__device__ __forceinline__ void gl_lds16(const void* g, void* l) {
  __builtin_amdgcn_global_load_lds(
      (const __attribute__((address_space(1))) void*)g,
      (__attribute__((address_space(3))) void*)l, 16, 0, 0);
}

// ============================ CSR build ============================
__global__ void hist_kernel(const int* __restrict__ dst0, const int* __restrict__ dst1,
                            int* __restrict__ counts) {
  int t = blockIdx.y;
  int e = blockIdx.x * blockDim.x + threadIdx.x;
  if (e >= NEDGE) return;
  const int* dst = t ? dst1 : dst0;
  atomicAdd(&counts[t * N_NODES + dst[e]], 1);
}

__launch_bounds__(1024)
__global__ void scan_kernel(const int* __restrict__ counts, int* __restrict__ row_ptr,
                            int* __restrict__ cursor) {
  int t = blockIdx.x;
  int tid = threadIdx.x;
  int lane = tid & 63, wv = tid >> 6;  // 16 waves
  __shared__ int wsum[16];
  int carry = 0;
  for (int base = 0; base < N_NODES; base += 1024) {
    int i = base + tid;
    int v = (i < N_NODES) ? counts[t * N_NODES + i] : 0;
    int x = v;
#pragma unroll
    for (int off = 1; off < 64; off <<= 1) {
      int u = __shfl_up(x, off);
      if (lane >= off) x += u;
    }
    if (lane == 63) wsum[wv] = x;
    __syncthreads();
    if (wv == 0 && lane < 16) {
      int y = wsum[lane];
#pragma unroll
      for (int off = 1; off < 16; off <<= 1) {
        int u = __shfl_up(y, off);
        if (lane >= off) y += u;
      }
      wsum[lane] = y;
    }
    __syncthreads();
    int blockoff = wv ? wsum[wv - 1] : 0;
    int tot = wsum[15];
    int excl = carry + blockoff + x - v;
    if (i < N_NODES) {
      row_ptr[t * (N_NODES + 1) + i] = excl;
      cursor[t * N_NODES + i] = excl;
    }
    carry += tot;
    __syncthreads();
  }
  if (tid == 0) row_ptr[t * (N_NODES + 1) + N_NODES] = carry;
}

__global__ void scatter_kernel(const int* __restrict__ src0, const int* __restrict__ dst0,
                               const int* __restrict__ src1, const int* __restrict__ dst1,
                               int* __restrict__ cursor, int* __restrict__ srcs) {
  int t = blockIdx.y;
  int e = blockIdx.x * blockDim.x + threadIdx.x;
  if (e >= NEDGE) return;
  const int* src = t ? src1 : src0;
  const int* dst = t ? dst1 : dst0;
  int d = dst[e];
  int pos = atomicAdd(&cursor[t * N_NODES + d], 1);
  srcs[t * NEDGE + pos] = src[e];
}

// ============================ prep: feats fp32 -> bf16 hi/lo ============================
__global__ void prep_feats_kernel(const float* __restrict__ f, u16* __restrict__ fh,
                                  u16* __restrict__ fl) {
  long i = ((long)blockIdx.x * blockDim.x + threadIdx.x) * 4;
  if (i >= (long)N_NODES * F_IN) return;
  float4 v = *(const float4*)(f + i);
  ushort4 hi, lo;
  bsplit(v.x, hi.x, lo.x);
  bsplit(v.y, hi.y, lo.y);
  bsplit(v.z, hi.z, lo.z);
  bsplit(v.w, hi.w, lo.w);
  *(ushort4*)(fh + i) = hi;
  *(ushort4*)(fl + i) = lo;
}

// ============================ weight prep: transpose + bf16 hi/lo split ============================
// W[t][K][256] fp32  ->  Bth/Btl[t][256][K] bf16
__launch_bounds__(256)
__global__ void prep_b_kernel(const float* __restrict__ W, u16* __restrict__ bth,
                              u16* __restrict__ btl, int K) {
  __shared__ unsigned tile[64][65];
  const int kt = blockIdx.x * 64, nt = blockIdx.y * 64, t = blockIdx.z;
  const int tid = threadIdx.x;
  const float* Wt = W + (size_t)t * K * 256;
  {
    int k = tid >> 2;
    int ncl = (tid & 3) * 16;
#pragma unroll
    for (int q = 0; q < 4; ++q) {
      float4 v = *(const float4*)(Wt + (size_t)(kt + k) * 256 + nt + ncl + q * 4);
      float f[4] = {v.x, v.y, v.z, v.w};
#pragma unroll
      for (int e = 0; e < 4; ++e) {
        u16 hi, lo;
        bsplit(f[e], hi, lo);
        tile[k][ncl + q * 4 + e] = (unsigned)hi | ((unsigned)lo << 16);
      }
    }
  }
  __syncthreads();
  {
    int n = tid & 63;
    int kc = (tid >> 6) * 16;
    u16 hi16[16], lo16[16];
#pragma unroll
    for (int i = 0; i < 16; ++i) {
      unsigned u = tile[kc + i][n];
      hi16[i] = (u16)(u & 0xffff);
      lo16[i] = (u16)(u >> 16);
    }
    size_t ob = ((size_t)t * 256 + nt + n) * K + kt + kc;
    *(s16x8*)(bth + ob)     = *(s16x8*)&hi16[0];
    *(s16x8*)(bth + ob + 8) = *(s16x8*)&hi16[8];
    *(s16x8*)(btl + ob)     = *(s16x8*)&lo16[0];
    *(s16x8*)(btl + ob + 8) = *(s16x8*)&lo16[8];
  }
}

// ============================ MFMA GEMM (bf16 3-term split) ============================
// MODE 0: GAT  — fused el/er (plain stores, single writer per slot)
// MODE 1: plain P = A@W (no bias)
// MODE 2: A = fp32 with BN scale/shift + relu transform; out = relu(acc + bias)
// ASPLIT: A given as pre-split bf16 hi/lo (1 or 2 K-sources), staged via global_load_lds
// OUTK: 0 = fp32 (Cf, +colOff), 1 = bf16 hi/lo split (Ch/Cl), 2 = fp16 (Ch)
// Tile BM=128,BN=128,BK=32; 4 waves (2x2), 64x64 per wave.
// LDS = 32 KB (4 buffers x 8 KB) -> ~4 blocks/CU (was 64 KB / 2 blocks: Occ 18%).
// Chunk-major planes: plane c (k-octet) stride 2048B, row stride 16B — conflict-free,
// linear in lane order so global_load_lds (wave-uniform dest + lane*16) works.
// ASPLIT staging: wave w fills buffer w (0=Ah,1=Al,2=Bh,3=Bl), 8 x 1KB chunks.
template <int MODE, bool ASPLIT, int OUTK>
__launch_bounds__(256)
__global__ void gemm_mfma(const float* __restrict__ Af,
                          const u16* __restrict__ A1h, const u16* __restrict__ A1l,
                          long strideA1, int ldA1, int KA1,
                          const u16* __restrict__ A2h, const u16* __restrict__ A2l,
                          long strideA2, int ldA2,
                          long strideAf, int K,
                          const u16* __restrict__ Bth, const u16* __restrict__ Btl,
                          const float* __restrict__ bias,
                          float* __restrict__ Cf, u16* __restrict__ Ch, u16* __restrict__ Cl,
                          long strideC, int ldC, int colOffT,
                          const float* __restrict__ al, const float* __restrict__ arv,
                          float* __restrict__ el, float* __restrict__ er,
                          const float* __restrict__ bnscale, const float* __restrict__ bnshift,
                          int M) {
  __shared__ __align__(16) char lds[32768];
  char* Ah = lds;
  char* Al = lds + 8192;
  char* Bh = lds + 16384;
  char* Bl = lds + 24576;

  const int t  = blockIdx.z;
  const int m0 = blockIdx.x * 128;
  const int n0 = blockIdx.y * 128;
  const int tid = threadIdx.x;
  const int lane = tid & 63;
  const int wid = tid >> 6;
  const int wm = wid >> 1, wn = wid & 1;
  const int lm = lane & 15, lg = lane >> 4;

  f32x4 acc[4][4];
#pragma unroll
  for (int i = 0; i < 4; ++i)
#pragma unroll
    for (int j = 0; j < 4; ++j) acc[i][j] = (f32x4)(0.f);

  // reg-staging assignment (MODE 2 only): row ar2, 16-float half akh
  const int ar2 = tid >> 1, akh = tid & 1;
  const bool avalid = (m0 + ar2) < M;
  const float* bsc = (MODE == 2) ? bnscale + (long)t * K : nullptr;
  const float* bsh = (MODE == 2) ? bnshift + (long)t * K : nullptr;

  for (int k0 = 0; k0 < K; k0 += 32) {
    if (k0) __syncthreads();
    if (ASPLIT) {
      // ---- wave `wid` fills buffer `wid`: 8 x gl_lds16 ----
      int rowA = m0 + lane;            // halves add 64
      if (rowA > M - 1) rowA = M - 1;
      int rowA2 = m0 + 64 + lane;
      if (rowA2 > M - 1) rowA2 = M - 1;
#pragma unroll
      for (int q = 0; q < 8; ++q) {
        int c = q >> 1, half = q & 1;
        if (wid < 2) {
          int r = half ? rowA2 : rowA;
          const u16* ga;
          if (k0 < KA1)
            ga = (wid == 0 ? A1h : A1l) + (long)t * strideA1 + (long)r * ldA1 + k0 + c * 8;
          else
            ga = (wid == 0 ? A2h : A2l) + (long)t * strideA2 + (long)r * ldA2 + (k0 - KA1) + c * 8;
          gl_lds16(ga, (wid == 0 ? Ah : Al) + c * 2048 + half * 1024);
        } else {
          int n = n0 + half * 64 + lane;
          const u16* gb = (wid == 2 ? Bth : Btl) + ((size_t)t * 256 + n) * K + k0 + c * 8;
          gl_lds16(gb, (wid == 2 ? Bh : Bl) + c * 2048 + half * 1024);
        }
      }
    } else {
      // ---- B via global_load_lds (4 loads/wave) ----
#pragma unroll
      for (int q = 0; q < 4; ++q) {
        int v = wid * 4 + q;           // 0..15
        bool hibuf = v < 8;
        int u = v & 7;
        int c = u >> 1, half = u & 1;
        int n = n0 + half * 64 + lane;
        const u16* gb = (hibuf ? Bth : Btl) + ((size_t)t * 256 + n) * K + k0 + c * 8;
        gl_lds16(gb, (hibuf ? Bh : Bl) + c * 2048 + half * 1024);
      }
      // ---- A: fp32 load + BN transform + split + ds_write (16 floats/thread) ----
      float fv[16];
      const float* ap = Af + (long)t * strideAf + (long)(m0 + ar2) * ldA1 + k0 + akh * 16;
#pragma unroll
      for (int q = 0; q < 4; ++q) {
        float4 v = make_float4(0.f, 0.f, 0.f, 0.f);
        if (avalid) {
          v = *(const float4*)(ap + q * 4);
          if (MODE == 2) {
            int kb = k0 + akh * 16 + q * 4;
            float4 sc = *(const float4*)(bsc + kb);
            float4 sh = *(const float4*)(bsh + kb);
            v.x = fmaxf(fmaf(v.x, sc.x, sh.x), 0.f);
            v.y = fmaxf(fmaf(v.y, sc.y, sh.y), 0.f);
            v.z = fmaxf(fmaf(v.z, sc.z, sh.z), 0.f);
            v.w = fmaxf(fmaf(v.w, sc.w, sh.w), 0.f);
          }
        }
        fv[q * 4 + 0] = v.x; fv[q * 4 + 1] = v.y; fv[q * 4 + 2] = v.z; fv[q * 4 + 3] = v.w;
      }
#pragma unroll
      for (int cl_ = 0; cl_ < 2; ++cl_) {
        u16 hi[8], lo[8];
#pragma unroll
        for (int e = 0; e < 8; ++e) bsplit(fv[cl_ * 8 + e], hi[e], lo[e]);
        int off = (akh * 2 + cl_) * 2048 + ar2 * 16;
        *(s16x8*)(Ah + off) = *(s16x8*)&hi[0];
        *(s16x8*)(Al + off) = *(s16x8*)&lo[0];
      }
    }
    __syncthreads();
    // ---- MFMA: chunk c = lane-group covers full k=32 ----
    {
      int c = lg;
      s16x8 fAh[4], fAl[4], fBh[4], fBl[4];
#pragma unroll
      for (int i = 0; i < 4; ++i) {
        int off = c * 2048 + (wm * 64 + i * 16 + lm) * 16;
        fAh[i] = *(const s16x8*)(Ah + off);
        fAl[i] = *(const s16x8*)(Al + off);
      }
#pragma unroll
      for (int j = 0; j < 4; ++j) {
        int off = c * 2048 + (wn * 64 + j * 16 + lm) * 16;
        fBh[j] = *(const s16x8*)(Bh + off);
        fBl[j] = *(const s16x8*)(Bl + off);
      }
#pragma unroll
      for (int i = 0; i < 4; ++i)
#pragma unroll
        for (int j = 0; j < 4; ++j) {
          acc[i][j] = __builtin_amdgcn_mfma_f32_16x16x32_bf16(fAh[i], fBh[j], acc[i][j], 0, 0, 0);
          acc[i][j] = __builtin_amdgcn_mfma_f32_16x16x32_bf16(fAh[i], fBl[j], acc[i][j], 0, 0, 0);
          acc[i][j] = __builtin_amdgcn_mfma_f32_16x16x32_bf16(fAl[i], fBh[j], acc[i][j], 0, 0, 0);
        }
    }
  }

  // ---- epilogue ----
  if (MODE == 0) {
    const float* alt = al + t * HIDDEN;
    const float* art = arv + t * HIDDEN;
    const int head = (n0 + wn * 64) >> 6;
    float av[4], rv[4];
#pragma unroll
    for (int j = 0; j < 4; ++j) {
      int gc = n0 + wn * 64 + j * 16 + lm;
      av[j] = alt[gc];
      rv[j] = art[gc];
    }
#pragma unroll
    for (int i = 0; i < 4; ++i)
#pragma unroll
      for (int r = 0; r < 4; ++r) {
        float pel = 0.f, per = 0.f;
#pragma unroll
        for (int j = 0; j < 4; ++j) {
          pel = fmaf(acc[i][j][r], av[j], pel);
          per = fmaf(acc[i][j][r], rv[j], per);
        }
#pragma unroll
        for (int o = 1; o < 16; o <<= 1) {
          pel += __shfl_xor(pel, o);
          per += __shfl_xor(per, o);
        }
        int row = m0 + wm * 64 + i * 16 + lg * 4 + r;
        if (lm == 0 && row < M) {
          el[((long)t * N_NODES + row) * 4 + head] = pel;  // single writer
          er[((long)t * N_NODES + row) * 4 + head] = per;
        }
      }
  }

  float bv[4];
  if (MODE == 2) {
#pragma unroll
    for (int j = 0; j < 4; ++j) bv[j] = bias[t * HIDDEN + n0 + wn * 64 + j * 16 + lm];
  }
  const int colOff = colOffT * t;
#pragma unroll
  for (int i = 0; i < 4; ++i)
#pragma unroll
    for (int r = 0; r < 4; ++r) {
      int row = m0 + wm * 64 + i * 16 + lg * 4 + r;
      if (row < M) {
#pragma unroll
        for (int j = 0; j < 4; ++j) {
          int col = n0 + wn * 64 + j * 16 + lm;
          float v = acc[i][j][r];
          if (MODE == 2) v = fmaxf(v + bv[j], 0.f);
          if (OUTK == 1) {
            u16 hi, lo;
            bsplit(v, hi, lo);
            Ch[(long)t * strideC + (long)row * ldC + col] = hi;
            Cl[(long)t * strideC + (long)row * ldC + col] = lo;
          } else if (OUTK == 2) {
            Ch[(long)t * strideC + (long)row * ldC + col] = f2h(v);
          } else {
            Cf[(long)t * strideC + colOff + (long)row * ldC + col] = v;
          }
        }
      }
    }
}

// ============================ GAT aggregation (z fp16 in, bf16 hi/lo out) ============================
// Fast path (deg<=64): lane j owns edge beg+j; el read ONCE, softmax weights kept in
// registers and broadcast via __shfl in the weighted pass — removes the per-edge el
// gather + exp recompute from the serial critical path. Fallback: 3-pass (deg>64).
__launch_bounds__(256)
__global__ void gat_agg_kernel(const u16* __restrict__ z, const float* __restrict__ el,
                               const float* __restrict__ er, const int* __restrict__ row_ptr,
                               const int* __restrict__ srcs, const float* __restrict__ bias,
                               u16* __restrict__ Hh, u16* __restrict__ Hl) {
  int t = blockIdx.y;
  int wv = threadIdx.x >> 6, lane = threadIdx.x & 63;
  int dst = blockIdx.x * 4 + wv;
  if (dst >= N_NODES) return;
  const int* rp = row_ptr + t * (N_NODES + 1);
  int beg = rp[dst], end = rp[dst + 1];
  int deg = end - beg;
  const float* elt = el + (long)t * N_NODES * 4;
  const u16* zt  = z + (long)t * N_NODES * HIDDEN;
  const int* st = srcs + (long)t * NEDGE;
  float4 erd = *(const float4*)(er + (long)t * N_NODES * 4 + ((long)dst << 2));
  int hl = lane >> 4;
  float a0 = 0, a1 = 0, a2 = 0, a3 = 0;
  float inv;

  if (deg <= 64) {
    int s_r = 0;
    float p0 = -INFINITY, p1 = -INFINITY, p2 = -INFINITY, p3 = -INFINITY;
    if (lane < deg) {
      s_r = st[beg + lane];
      float4 ev = *(const float4*)(elt + ((unsigned)s_r << 2));
      p0 = lrelu(ev.x + erd.x);
      p1 = lrelu(ev.y + erd.y);
      p2 = lrelu(ev.z + erd.z);
      p3 = lrelu(ev.w + erd.w);
    }
    float m0 = p0, m1 = p1, m2 = p2, m3 = p3;
#pragma unroll
    for (int off = 32; off; off >>= 1) {
      m0 = fmaxf(m0, __shfl_xor(m0, off));
      m1 = fmaxf(m1, __shfl_xor(m1, off));
      m2 = fmaxf(m2, __shfl_xor(m2, off));
      m3 = fmaxf(m3, __shfl_xor(m3, off));
    }
    p0 = (lane < deg) ? __expf(p0 - m0) : 0.f;
    p1 = (lane < deg) ? __expf(p1 - m1) : 0.f;
    p2 = (lane < deg) ? __expf(p2 - m2) : 0.f;
    p3 = (lane < deg) ? __expf(p3 - m3) : 0.f;
    float d0 = p0, d1 = p1, d2 = p2, d3 = p3;
#pragma unroll
    for (int off = 32; off; off >>= 1) {
      d0 += __shfl_xor(d0, off);
      d1 += __shfl_xor(d1, off);
      d2 += __shfl_xor(d2, off);
      d3 += __shfl_xor(d3, off);
    }
    float dh = (hl == 0) ? d0 : (hl == 1) ? d1 : (hl == 2) ? d2 : d3;
    inv = 1.0f / fmaxf(dh, 1e-9f);
    for (int j = 0; j < deg; ++j) {
      unsigned s = (unsigned)__shfl(s_r, j);
      float w0 = __shfl(p0, j), w1 = __shfl(p1, j);
      float w2 = __shfl(p2, j), w3 = __shfl(p3, j);
      float w = ((hl == 0) ? w0 : (hl == 1) ? w1 : (hl == 2) ? w2 : w3) * inv;
      uint2 zp = *(const uint2*)(zt + (s << 8) + (lane << 2));
      float2 f0 = __half22float2(*(__half2*)&zp.x);
      float2 f1 = __half22float2(*(__half2*)&zp.y);
      a0 = fmaf(w, f0.x, a0);
      a1 = fmaf(w, f0.y, a1);
      a2 = fmaf(w, f1.x, a2);
      a3 = fmaf(w, f1.y, a3);
    }
  } else {
    // -------- fallback: original 3-pass --------
    float m0 = -INFINITY, m1 = -INFINITY, m2 = -INFINITY, m3 = -INFINITY;
    for (int j = beg + lane; j < end; j += 64) {
      unsigned s = (unsigned)st[j];
      float4 ev = *(const float4*)(elt + (s << 2));
      m0 = fmaxf(m0, lrelu(ev.x + erd.x));
      m1 = fmaxf(m1, lrelu(ev.y + erd.y));
      m2 = fmaxf(m2, lrelu(ev.z + erd.z));
      m3 = fmaxf(m3, lrelu(ev.w + erd.w));
    }
#pragma unroll
    for (int off = 32; off; off >>= 1) {
      m0 = fmaxf(m0, __shfl_xor(m0, off));
      m1 = fmaxf(m1, __shfl_xor(m1, off));
      m2 = fmaxf(m2, __shfl_xor(m2, off));
      m3 = fmaxf(m3, __shfl_xor(m3, off));
    }
    float d0 = 0, d1 = 0, d2 = 0, d3 = 0;
    for (int j = beg + lane; j < end; j += 64) {
      unsigned s = (unsigned)st[j];
      float4 ev = *(const float4*)(elt + (s << 2));
      d0 += __expf(lrelu(ev.x + erd.x) - m0);
      d1 += __expf(lrelu(ev.y + erd.y) - m1);
      d2 += __expf(lrelu(ev.z + erd.z) - m2);
      d3 += __expf(lrelu(ev.w + erd.w) - m3);
    }
#pragma unroll
    for (int off = 32; off; off >>= 1) {
      d0 += __shfl_xor(d0, off);
      d1 += __shfl_xor(d1, off);
      d2 += __shfl_xor(d2, off);
      d3 += __shfl_xor(d3, off);
    }
    float mh  = (hl == 0) ? m0 : (hl == 1) ? m1 : (hl == 2) ? m2 : m3;
    float dh  = (hl == 0) ? d0 : (hl == 1) ? d1 : (hl == 2) ? d2 : d3;
    float erh = (hl == 0) ? erd.x : (hl == 1) ? erd.y : (hl == 2) ? erd.z : erd.w;
    inv = 1.0f / fmaxf(dh, 1e-9f);
    for (int j = beg; j < end; ++j) {
      unsigned s = (unsigned)st[j];
      float eh = lrelu(elt[(s << 2) + hl] + erh);
      float w = __expf(eh - mh) * inv;
      uint2 zp = *(const uint2*)(zt + (s << 8) + (lane << 2));
      float2 f0 = __half22float2(*(__half2*)&zp.x);
      float2 f1 = __half22float2(*(__half2*)&zp.y);
      a0 = fmaf(w, f0.x, a0);
      a1 = fmaf(w, f0.y, a1);
      a2 = fmaf(w, f1.x, a2);
      a3 = fmaf(w, f1.y, a3);
    }
  }

  float4 bv = *(const float4*)(bias + t * HIDDEN + lane * 4);
  float o0 = fmaxf(a0 + bv.x, 0.f);
  float o1 = fmaxf(a1 + bv.y, 0.f);
  float o2 = fmaxf(a2 + bv.z, 0.f);
  float o3 = fmaxf(a3 + bv.w, 0.f);
  ushort4 hi, lo;
  bsplit(o0, hi.x, lo.x);
  bsplit(o1, hi.y, lo.y);
  bsplit(o2, hi.z, lo.z);
  bsplit(o3, hi.w, lo.w);
  long ob = (long)t * N_NODES * HIDDEN + (long)dst * HIDDEN + lane * 4;
  *(ushort4*)(Hh + ob) = hi;
  *(ushort4*)(Hl + ob) = lo;
}

// ============================ GIN aggregation on P (fp16 in, fp32 out) ============================
// y = (1+eps)*P[dst] + sum_{src} P[src] + b1
__launch_bounds__(256)
__global__ void gin_agg_kernel(const u16* __restrict__ P, const int* __restrict__ row_ptr,
                               const int* __restrict__ srcs, const float* __restrict__ epsArr,
                               const float* __restrict__ b1, float* __restrict__ y) {
  int t = blockIdx.y;
  int wv = threadIdx.x >> 6, lane = threadIdx.x & 63;
  int dst = blockIdx.x * 4 + wv;
  if (dst >= N_NODES) return;
  const int* rp = row_ptr + t * (N_NODES + 1);
  int beg = rp[dst], end = rp[dst + 1];
  const u16* Pt = P + (long)t * N_NODES * HIDDEN;
  const int* st = srcs + (long)t * NEDGE;
  float ep = 1.0f + epsArr[t];
  float a0 = 0, a1 = 0, a2 = 0, a3 = 0;
  for (int j = beg; j < end; ++j) {
    unsigned s = (unsigned)st[j];
    uint2 pp = *(const uint2*)(Pt + (s << 8) + (lane << 2));
    float2 f0 = __half22float2(*(__half2*)&pp.x);
    float2 f1 = __half22float2(*(__half2*)&pp.y);
    a0 += f0.x; a1 += f0.y; a2 += f1.x; a3 += f1.y;
  }
  uint2 sp = *(const uint2*)(Pt + ((unsigned)dst << 8) + (lane << 2));
  float2 s0 = __half22float2(*(__half2*)&sp.x);
  float2 s1 = __half22float2(*(__half2*)&sp.y);
  float4 bb = *(const float4*)(b1 + t * HIDDEN + lane * 4);
  float4 o;
  o.x = fmaf(ep, s0.x, a0) + bb.x;
  o.y = fmaf(ep, s0.y, a1) + bb.y;
  o.z = fmaf(ep, s1.x, a2) + bb.z;
  o.w = fmaf(ep, s1.y, a3) + bb.w;
  *(float4*)(y + (long)t * N_NODES * HIDDEN + (long)dst * HIDDEN + lane * 4) = o;
}

// ============================ BN stats (two-level, no atomics) ============================
__launch_bounds__(256)
__global__ void stats_kernel(const float* __restrict__ y, long strideY,
                             float* __restrict__ partials) {  // [T][SNB][512]
  const int t = blockIdx.y, blk = blockIdx.x;
  const int tid = threadIdx.x;
  const int col4 = (tid & 63) * 4;
  const int rsub = tid >> 6;
  const int chunk = (N_NODES + SNB - 1) / SNB;
  const int r0 = blk * chunk;
  const int rend = min(r0 + chunk, N_NODES);
  const float* yt = y + (long)t * strideY;
  float s[4] = {0.f, 0.f, 0.f, 0.f}, s2[4] = {0.f, 0.f, 0.f, 0.f};
  for (int r = r0 + rsub; r < rend; r += 4) {
    float4 v = *(const float4*)(yt + (long)r * HIDDEN + col4);
    s[0] += v.x; s2[0] = fmaf(v.x, v.x, s2[0]);
    s[1] += v.y; s2[1] = fmaf(v.y, v.y, s2[1]);
    s[2] += v.z; s2[2] = fmaf(v.z, v.z, s2[2]);
    s[3] += v.w; s2[3] = fmaf(v.w, v.w, s2[3]);
  }
  __shared__ float ls[4][512];
#pragma unroll
  for (int e = 0; e < 4; ++e) {
    ls[rsub][col4 + e] = s[e];
    ls[rsub][256 + col4 + e] = s2[e];
  }
  __syncthreads();
  for (int i = tid; i < 512; i += 256) {
    float v = ls[0][i] + ls[1][i] + ls[2][i] + ls[3][i];
    partials[((long)t * SNB + blk) * 512 + i] = v;
  }
}

__global__ void bn_finalize_kernel(const float* __restrict__ partials,
                                   const float* __restrict__ g1, const float* __restrict__ be1,
                                   float* __restrict__ scale, float* __restrict__ shift) {
  int i = threadIdx.x + blockIdx.x * blockDim.x;
  if (i >= NTYPE * HIDDEN) return;
  int t = i / HIDDEN, c = i % HIDDEN;
  float s = 0.f, s2 = 0.f;
  for (int b = 0; b < SNB; ++b) {
    s  += partials[((long)t * SNB + b) * 512 + c];
    s2 += partials[((long)t * SNB + b) * 512 + 256 + c];
  }
  float mu  = s * (1.0f / N_NODES);
  float ms  = s2 * (1.0f / N_NODES);
  float var = ms - mu * mu;
  float sc = g1[i] * rsqrtf(var + 1e-5f);
  scale[i] = sc;
  shift[i] = be1[i] - mu * sc;
}

// ============================ launch ============================
extern "C" void kernel_launch(void* const* d_in, const int* in_sizes, int n_in,
                              void* d_out, int out_size, void* d_ws, size_t ws_size,
                              hipStream_t stream) {
  const float* feats   = (const float*)d_in[0];
  const int* src0      = (const int*)d_in[1];
  const int* dst0      = (const int*)d_in[2];
  const int* src1      = (const int*)d_in[3];
  const int* dst1      = (const int*)d_in[4];
  const float* gat0_W  = (const float*)d_in[5];
  const float* gat0_al = (const float*)d_in[6];
  const float* gat0_ar = (const float*)d_in[7];
  const float* gat0_b  = (const float*)d_in[8];
  const float* gat1_W  = (const float*)d_in[9];
  const float* gat1_al = (const float*)d_in[10];
  const float* gat1_ar = (const float*)d_in[11];
  const float* gat1_b  = (const float*)d_in[12];
  const float* gin0_eps = (const float*)d_in[13];
  const float* gin0_W1  = (const float*)d_in[14];
  const float* gin0_b1  = (const float*)d_in[15];
  const float* gin0_g1  = (const float*)d_in[16];
  const float* gin0_be1 = (const float*)d_in[17];
  const float* gin0_W2  = (const float*)d_in[18];
  const float* gin0_b2  = (const float*)d_in[19];
  const float* gin1_eps = (const float*)d_in[20];
  const float* gin1_W1  = (const float*)d_in[21];
  const float* gin1_b1  = (const float*)d_in[22];
  const float* gin1_g1  = (const float*)d_in[23];
  const float* gin1_be1 = (const float*)d_in[24];
  const float* gin1_W2  = (const float*)d_in[25];
  const float* gin1_b2  = (const float*)d_in[26];
  float* out = (float*)d_out;

  char* p = (char*)d_ws;
  size_t off = 0;
  auto take = [&](size_t bytes) -> void* {
    void* r = p + off;
    off = (off + bytes + 255) & ~(size_t)255;
    return r;
  };
  float* bufA  = (float*)take((size_t)NTYPE * N_NODES * HIDDEN * 4);  // y (fp32)
  u16*   bufZ  = (u16*)take((size_t)NTYPE * N_NODES * HIDDEN * 2);    // z / P (fp16)
  u16*   bufCh = (u16*)take((size_t)NTYPE * N_NODES * HIDDEN * 2);    // h hi (bf16)
  u16*   bufCl = (u16*)take((size_t)NTYPE * N_NODES * HIDDEN * 2);    // h lo
  u16*   fhi   = (u16*)take((size_t)N_NODES * F_IN * 2);
  u16*   flo   = (u16*)take((size_t)N_NODES * F_IN * 2);
  float* el   = (float*)take((size_t)NTYPE * N_NODES * 4 * 4);
  float* er   = (float*)take((size_t)NTYPE * N_NODES * 4 * 4);
  int* counts  = (int*)take((size_t)NTYPE * N_NODES * 4);
  int* row_ptr = (int*)take((size_t)NTYPE * (N_NODES + 1) * 4);
  int* cursor  = (int*)take((size_t)NTYPE * N_NODES * 4);
  int* srcs    = (int*)take((size_t)NTYPE * NEDGE * 4);
  float* bn_part  = (float*)take((size_t)NTYPE * SNB * 512 * 4);
  float* bn_scale = (float*)take((size_t)NTYPE * HIDDEN * 4);
  float* bn_shift = (float*)take((size_t)NTYPE * HIDDEN * 4);
  u16* bh_g0   = (u16*)take((size_t)NTYPE * 256 * 128 * 2);
  u16* bl_g0   = (u16*)take((size_t)NTYPE * 256 * 128 * 2);
  u16* bh_g1   = (u16*)take((size_t)NTYPE * 256 * 256 * 2);
  u16* bl_g1   = (u16*)take((size_t)NTYPE * 256 * 256 * 2);
  u16* bh_i0w1 = (u16*)take((size_t)NTYPE * 256 * 384 * 2);
  u16* bl_i0w1 = (u16*)take((size_t)NTYPE * 256 * 384 * 2);
  u16* bh_i0w2 = (u16*)take((size_t)NTYPE * 256 * 256 * 2);
  u16* bl_i0w2 = (u16*)take((size_t)NTYPE * 256 * 256 * 2);
  u16* bh_i1w1 = (u16*)take((size_t)NTYPE * 256 * 256 * 2);
  u16* bl_i1w1 = (u16*)take((size_t)NTYPE * 256 * 256 * 2);
  u16* bh_i1w2 = (u16*)take((size_t)NTYPE * 256 * 256 * 2);
  u16* bl_i1w2 = (u16*)take((size_t)NTYPE * 256 * 256 * 2);
  (void)ws_size; (void)in_sizes; (void)n_in; (void)out_size;

  const dim3 blk(256);
  const int egrid = (NEDGE + 255) / 256;
  const dim3 ggrid((N_NODES + 127) / 128, 2, NTYPE);
  const dim3 agrid((N_NODES + 3) / 4, NTYPE);
  const dim3 sgrid(SNB, NTYPE);
  const long sN256 = (long)N_NODES * HIDDEN;

  // ---- prep ----
  prep_feats_kernel<<<(N_NODES * F_IN / 4 + 255) / 256, blk, 0, stream>>>(feats, fhi, flo);
  prep_b_kernel<<<dim3(2, 4, NTYPE), blk, 0, stream>>>(gat0_W, bh_g0, bl_g0, 128);
  prep_b_kernel<<<dim3(4, 4, NTYPE), blk, 0, stream>>>(gat1_W, bh_g1, bl_g1, 256);
  prep_b_kernel<<<dim3(6, 4, NTYPE), blk, 0, stream>>>(gin0_W1, bh_i0w1, bl_i0w1, 384);
  prep_b_kernel<<<dim3(4, 4, NTYPE), blk, 0, stream>>>(gin0_W2, bh_i0w2, bl_i0w2, 256);
  prep_b_kernel<<<dim3(4, 4, NTYPE), blk, 0, stream>>>(gin1_W1, bh_i1w1, bl_i1w1, 256);
  prep_b_kernel<<<dim3(4, 4, NTYPE), blk, 0, stream>>>(gin1_W2, bh_i1w2, bl_i1w2, 256);

  // ---- CSR build ----
  hipMemsetAsync(counts, 0, (size_t)NTYPE * N_NODES * 4, stream);
  hist_kernel<<<dim3(egrid, NTYPE), blk, 0, stream>>>(dst0, dst1, counts);
  scan_kernel<<<NTYPE, 1024, 0, stream>>>(counts, row_ptr, cursor);
  scatter_kernel<<<dim3(egrid, NTYPE), blk, 0, stream>>>(src0, dst0, src1, dst1, cursor, srcs);

  // ---- GAT layer 0 ----
  gemm_mfma<0, true, 2><<<ggrid, blk, 0, stream>>>(nullptr,
      fhi, flo, 0L, F_IN, F_IN, nullptr, nullptr, 0L, 0, 0L, F_IN,
      bh_g0, bl_g0, nullptr, nullptr, bufZ, nullptr, sN256, HIDDEN, 0,
      gat0_al, gat0_ar, el, er, nullptr, nullptr, N_NODES);
  gat_agg_kernel<<<agrid, blk, 0, stream>>>(bufZ, el, er, row_ptr, srcs, gat0_b, bufCh, bufCl);

  // ---- GAT layer 1 ----
  gemm_mfma<0, true, 2><<<ggrid, blk, 0, stream>>>(nullptr,
      bufCh, bufCl, sN256, HIDDEN, HIDDEN, nullptr, nullptr, 0L, 0, 0L, HIDDEN,
      bh_g1, bl_g1, nullptr, nullptr, bufZ, nullptr, sN256, HIDDEN, 0,
      gat1_al, gat1_ar, el, er, nullptr, nullptr, N_NODES);
  gat_agg_kernel<<<agrid, blk, 0, stream>>>(bufZ, el, er, row_ptr, srcs, gat1_b, bufCh, bufCl);

  // ---- GIN layer 0: P = [h | feats] @ W1 (K=384), then aggregate P ----
  gemm_mfma<1, true, 2><<<ggrid, blk, 0, stream>>>(nullptr,
      bufCh, bufCl, sN256, HIDDEN, HIDDEN, fhi, flo, 0L, F_IN, 0L, HIDDEN + F_IN,
      bh_i0w1, bl_i0w1, nullptr, nullptr, bufZ, nullptr, sN256, HIDDEN, 0,
      nullptr, nullptr, nullptr, nullptr, nullptr, nullptr, N_NODES);
  gin_agg_kernel<<<agrid, blk, 0, stream>>>(bufZ, row_ptr, srcs, gin0_eps, gin0_b1, bufA);
  stats_kernel<<<sgrid, blk, 0, stream>>>(bufA, sN256, bn_part);
  bn_finalize_kernel<<<1, NTYPE * HIDDEN, 0, stream>>>(bn_part, gin0_g1, gin0_be1, bn_scale, bn_shift);
  gemm_mfma<2, false, 1><<<ggrid, blk, 0, stream>>>(bufA,
      nullptr, nullptr, 0L, HIDDEN, HIDDEN, nullptr, nullptr, 0L, 0, sN256, HIDDEN,
      bh_i0w2, bl_i0w2, gin0_b2, nullptr, bufCh, bufCl, sN256, HIDDEN, 0,
      nullptr, nullptr, nullptr, nullptr, bn_scale, bn_shift, N_NODES);

  // ---- GIN layer 1 ----
  gemm_mfma<1, true, 2><<<ggrid, blk, 0, stream>>>(nullptr,
      bufCh, bufCl, sN256, HIDDEN, HIDDEN, nullptr, nullptr, 0L, 0, 0L, HIDDEN,
      bh_i1w1, bl_i1w1, nullptr, nullptr, bufZ, nullptr, sN256, HIDDEN, 0,
      nullptr, nullptr, nullptr, nullptr, nullptr, nullptr, N_NODES);
  gin_agg_kernel<<<agrid, blk, 0, stream>>>(bufZ, row_ptr, srcs, gin1_eps, gin1_b1, bufA);
  stats_kernel<<<sgrid, blk, 0, stream>>>(bufA, sN256, bn_part);
  bn_finalize_kernel<<<1, NTYPE * HIDDEN, 0, stream>>>(bn_part, gin1_g1, gin1_be1, bn_scale, bn_shift);
  gemm_mfma<2, false, 0><<<ggrid, blk, 0, stream>>>(bufA,
      nullptr, nullptr, 0L, HIDDEN, HIDDEN, nullptr, nullptr, 0L, 0, sN256, HIDDEN,
      bh_i1w2, bl_i1w2, gin1_b2, out, nullptr, nullptr, 0L, NTYPE * HIDDEN, HIDDEN,
      nullptr, nullptr, nullptr, nullptr, bn_scale, bn_shift, N_NODES);
}

// Round 8
// 1149.974 us; speedup vs baseline: 1.2782x; 1.2782x over previous
//
#include <hip/hip_runtime.h>
#include <hip/hip_fp16.h>
#include <math.h>
#include <cstdint>

#define N_NODES 50000
#define F_IN    128
#define HIDDEN  256
#define NHEAD   4
#define HEADD   64
#define NEDGE   400000
#define NTYPE   2
#define SNB     256   // stats partial-reduction blocks per type

typedef unsigned short u16;
typedef float f32x4 __attribute__((ext_vector_type(4)));
typedef short s16x8 __attribute__((ext_vector_type(8)));

__device__ __forceinline__ float lrelu(float x) { return x > 0.f ? x : 0.2f * x; }

__device__ __forceinline__ u16 f2h(float f) {
  return __half_as_ushort(__float2half(f));
}

__device__ __forceinline__ void gl_lds16(const void* g, void* l) {
  __builtin_amdgcn_global_load_lds(
      (const __attribute__((address_space(1))) void*)g,
      (__attribute__((address_space(3))) void*)l, 16, 0, 0);
}

// ============================ CSR build ============================
__global__ void hist_kernel(const int* __restrict__ dst0, const int* __restrict__ dst1,
                            int* __restrict__ counts) {
  int t = blockIdx.y;
  int e = blockIdx.x * blockDim.x + threadIdx.x;
  if (e >= NEDGE) return;
  const int* dst = t ? dst1 : dst0;
  atomicAdd(&counts[t * N_NODES + dst[e]], 1);
}

__launch_bounds__(1024)
__global__ void scan_kernel(const int* __restrict__ counts, int* __restrict__ row_ptr,
                            int* __restrict__ cursor) {
  int t = blockIdx.x;
  int tid = threadIdx.x;
  int lane = tid & 63, wv = tid >> 6;  // 16 waves
  __shared__ int wsum[16];
  int carry = 0;
  for (int base = 0; base < N_NODES; base += 1024) {
    int i = base + tid;
    int v = (i < N_NODES) ? counts[t * N_NODES + i] : 0;
    int x = v;
#pragma unroll
    for (int off = 1; off < 64; off <<= 1) {
      int u = __shfl_up(x, off);
      if (lane >= off) x += u;
    }
    if (lane == 63) wsum[wv] = x;
    __syncthreads();
    if (wv == 0 && lane < 16) {
      int y = wsum[lane];
#pragma unroll
      for (int off = 1; off < 16; off <<= 1) {
        int u = __shfl_up(y, off);
        if (lane >= off) y += u;
      }
      wsum[lane] = y;
    }
    __syncthreads();
    int blockoff = wv ? wsum[wv - 1] : 0;
    int tot = wsum[15];
    int excl = carry + blockoff + x - v;
    if (i < N_NODES) {
      row_ptr[t * (N_NODES + 1) + i] = excl;
      cursor[t * N_NODES + i] = excl;
    }
    carry += tot;
    __syncthreads();
  }
  if (tid == 0) row_ptr[t * (N_NODES + 1) + N_NODES] = carry;
}

__global__ void scatter_kernel(const int* __restrict__ src0, const int* __restrict__ dst0,
                               const int* __restrict__ src1, const int* __restrict__ dst1,
                               int* __restrict__ cursor, int* __restrict__ srcs) {
  int t = blockIdx.y;
  int e = blockIdx.x * blockDim.x + threadIdx.x;
  if (e >= NEDGE) return;
  const int* src = t ? src1 : src0;
  const int* dst = t ? dst1 : dst0;
  int d = dst[e];
  int pos = atomicAdd(&cursor[t * N_NODES + d], 1);
  srcs[t * NEDGE + pos] = src[e];
}

// ============================ prep: feats fp32 -> fp16 ============================
__global__ void prep_feats_kernel(const float* __restrict__ f, u16* __restrict__ fh) {
  long i = ((long)blockIdx.x * blockDim.x + threadIdx.x) * 4;
  if (i >= (long)N_NODES * F_IN) return;
  float4 v = *(const float4*)(f + i);
  ushort4 h;
  h.x = f2h(v.x); h.y = f2h(v.y); h.z = f2h(v.z); h.w = f2h(v.w);
  *(ushort4*)(fh + i) = h;
}

// ============================ weight prep: transpose + fp16 ============================
// W[t][K][256] fp32  ->  Bt[t][256][K] fp16
__launch_bounds__(256)
__global__ void prep_b_kernel(const float* __restrict__ W, u16* __restrict__ bt, int K) {
  __shared__ u16 tile[64][72];
  const int kt = blockIdx.x * 64, nt = blockIdx.y * 64, t = blockIdx.z;
  const int tid = threadIdx.x;
  const float* Wt = W + (size_t)t * K * 256;
  {
    int k = tid >> 2;
    int ncl = (tid & 3) * 16;
#pragma unroll
    for (int q = 0; q < 4; ++q) {
      float4 v = *(const float4*)(Wt + (size_t)(kt + k) * 256 + nt + ncl + q * 4);
      tile[k][ncl + q * 4 + 0] = f2h(v.x);
      tile[k][ncl + q * 4 + 1] = f2h(v.y);
      tile[k][ncl + q * 4 + 2] = f2h(v.z);
      tile[k][ncl + q * 4 + 3] = f2h(v.w);
    }
  }
  __syncthreads();
  {
    int n = tid & 63;
    int kc = (tid >> 6) * 16;
    u16 o16[16];
#pragma unroll
    for (int i = 0; i < 16; ++i) o16[i] = tile[kc + i][n];
    size_t ob = ((size_t)t * 256 + nt + n) * K + kt + kc;
    *(s16x8*)(bt + ob)     = *(s16x8*)&o16[0];
    *(s16x8*)(bt + ob + 8) = *(s16x8*)&o16[8];
  }
}

// ============================ MFMA GEMM (fp16 inputs, fp32 accum) ============================
// MODE 0: GAT  — fused el/er (plain stores, single writer per slot)
// MODE 1: plain P = A@W (no bias)
// MODE 2: A = fp32 with BN scale/shift + relu transform; out = relu(acc + bias)
// ASPLIT: A given as fp16 (1 or 2 K-sources), staged via global_load_lds
// OUTK: 0 = fp32 (Cf, +colOff), 1 = fp16 (Ch)
// Tile BM=128,BN=128,BK=64; 4 waves (2x2), 64x64 per wave.
// LDS = 32 KB (A 16KB + B 16KB) -> ~5 blocks/CU. 32 MFMA / wave / k-step.
// Chunk-major planes: plane c (k-octet) stride 2048B, row stride 16B — conflict-free,
// linear in lane order so global_load_lds (wave-uniform dest + lane*16) works.
template <int MODE, bool ASPLIT, int OUTK>
__launch_bounds__(256)
__global__ void gemm_mfma(const float* __restrict__ Af,
                          const u16* __restrict__ A1, long strideA1, int ldA1, int KA1,
                          const u16* __restrict__ A2, long strideA2, int ldA2,
                          long strideAf, int K,
                          const u16* __restrict__ Bt,
                          const float* __restrict__ bias,
                          float* __restrict__ Cf, u16* __restrict__ Ch,
                          long strideC, int ldC, int colOffT,
                          const float* __restrict__ al, const float* __restrict__ arv,
                          float* __restrict__ el, float* __restrict__ er,
                          const float* __restrict__ bnscale, const float* __restrict__ bnshift,
                          int M) {
  __shared__ __align__(16) char lds[32768];
  char* As = lds;
  char* Bs = lds + 16384;

  const int t  = blockIdx.z;
  const int m0 = blockIdx.x * 128;
  const int n0 = blockIdx.y * 128;
  const int tid = threadIdx.x;
  const int lane = tid & 63;
  const int wid = tid >> 6;
  const int wm = wid >> 1, wn = wid & 1;
  const int lm = lane & 15, lg = lane >> 4;

  f32x4 acc[4][4];
#pragma unroll
  for (int i = 0; i < 4; ++i)
#pragma unroll
    for (int j = 0; j < 4; ++j) acc[i][j] = (f32x4)(0.f);

  // reg-staging assignment (MODE 2 only): row ar2, 32-float half akh
  const int ar2 = tid >> 1, akh = tid & 1;
  const bool avalid = (m0 + ar2) < M;
  const float* bsc = (MODE == 2) ? bnscale + (long)t * K : nullptr;
  const float* bsh = (MODE == 2) ? bnshift + (long)t * K : nullptr;

  for (int k0 = 0; k0 < K; k0 += 64) {
    if (k0) __syncthreads();
    if (ASPLIT) {
      // ---- A + B fully via global_load_lds: 8 loads/wave ----
#pragma unroll
      for (int q = 0; q < 8; ++q) {
        int v = wid * 8 + q;  // 0..31
        if (v < 16) {
          int c = v >> 1, half = v & 1;
          int rowA = m0 + half * 64 + lane;
          if (rowA > M - 1) rowA = M - 1;
          const u16* ga;
          if (k0 < KA1)
            ga = A1 + (long)t * strideA1 + (long)rowA * ldA1 + k0 + c * 8;
          else
            ga = A2 + (long)t * strideA2 + (long)rowA * ldA2 + (k0 - KA1) + c * 8;
          gl_lds16(ga, As + c * 2048 + half * 1024);
        } else {
          int u = v - 16;
          int c = u >> 1, half = u & 1;
          int n = n0 + half * 64 + lane;
          const u16* gb = Bt + ((size_t)t * 256 + n) * K + k0 + c * 8;
          gl_lds16(gb, Bs + c * 2048 + half * 1024);
        }
      }
    } else {
      // ---- B via global_load_lds (4 loads/wave) ----
#pragma unroll
      for (int q = 0; q < 4; ++q) {
        int v = wid * 4 + q;  // 0..15
        int c = v >> 1, half = v & 1;
        int n = n0 + half * 64 + lane;
        const u16* gb = Bt + ((size_t)t * 256 + n) * K + k0 + c * 8;
        gl_lds16(gb, Bs + c * 2048 + half * 1024);
      }
      // ---- A: fp32 load + BN transform + fp16 convert + ds_write (32 floats/thread) ----
      float fv[32];
      const float* ap = Af + (long)t * strideAf + (long)(m0 + ar2) * ldA1 + k0 + akh * 32;
#pragma unroll
      for (int q = 0; q < 8; ++q) {
        float4 v = make_float4(0.f, 0.f, 0.f, 0.f);
        if (avalid) {
          v = *(const float4*)(ap + q * 4);
          if (MODE == 2) {
            int kb = k0 + akh * 32 + q * 4;
            float4 sc = *(const float4*)(bsc + kb);
            float4 sh = *(const float4*)(bsh + kb);
            v.x = fmaxf(fmaf(v.x, sc.x, sh.x), 0.f);
            v.y = fmaxf(fmaf(v.y, sc.y, sh.y), 0.f);
            v.z = fmaxf(fmaf(v.z, sc.z, sh.z), 0.f);
            v.w = fmaxf(fmaf(v.w, sc.w, sh.w), 0.f);
          }
        }
        fv[q * 4 + 0] = v.x; fv[q * 4 + 1] = v.y; fv[q * 4 + 2] = v.z; fv[q * 4 + 3] = v.w;
      }
#pragma unroll
      for (int cl_ = 0; cl_ < 4; ++cl_) {
        u16 h[8];
#pragma unroll
        for (int e = 0; e < 8; ++e) h[e] = f2h(fv[cl_ * 8 + e]);
        int off = (akh * 4 + cl_) * 2048 + ar2 * 16;
        *(s16x8*)(As + off) = *(s16x8*)&h[0];
      }
    }
    __syncthreads();
    // ---- MFMA: 32 per wave per k-step ----
#pragma unroll
    for (int kk = 0; kk < 2; ++kk) {
      int c = kk * 4 + lg;
      s16x8 fA[4], fB[4];
#pragma unroll
      for (int i = 0; i < 4; ++i)
        fA[i] = *(const s16x8*)(As + c * 2048 + (wm * 64 + i * 16 + lm) * 16);
#pragma unroll
      for (int j = 0; j < 4; ++j)
        fB[j] = *(const s16x8*)(Bs + c * 2048 + (wn * 64 + j * 16 + lm) * 16);
#pragma unroll
      for (int i = 0; i < 4; ++i)
#pragma unroll
        for (int j = 0; j < 4; ++j)
          acc[i][j] = __builtin_amdgcn_mfma_f32_16x16x32_f16(fA[i], fB[j], acc[i][j], 0, 0, 0);
    }
  }

  // ---- epilogue ----
  if (MODE == 0) {
    const float* alt = al + t * HIDDEN;
    const float* art = arv + t * HIDDEN;
    const int head = (n0 + wn * 64) >> 6;
    float av[4], rv[4];
#pragma unroll
    for (int j = 0; j < 4; ++j) {
      int gc = n0 + wn * 64 + j * 16 + lm;
      av[j] = alt[gc];
      rv[j] = art[gc];
    }
#pragma unroll
    for (int i = 0; i < 4; ++i)
#pragma unroll
      for (int r = 0; r < 4; ++r) {
        float pel = 0.f, per = 0.f;
#pragma unroll
        for (int j = 0; j < 4; ++j) {
          pel = fmaf(acc[i][j][r], av[j], pel);
          per = fmaf(acc[i][j][r], rv[j], per);
        }
#pragma unroll
        for (int o = 1; o < 16; o <<= 1) {
          pel += __shfl_xor(pel, o);
          per += __shfl_xor(per, o);
        }
        int row = m0 + wm * 64 + i * 16 + lg * 4 + r;
        if (lm == 0 && row < M) {
          el[((long)t * N_NODES + row) * 4 + head] = pel;  // single writer
          er[((long)t * N_NODES + row) * 4 + head] = per;
        }
      }
  }

  float bv[4];
  if (MODE == 2) {
#pragma unroll
    for (int j = 0; j < 4; ++j) bv[j] = bias[t * HIDDEN + n0 + wn * 64 + j * 16 + lm];
  }
  const int colOff = colOffT * t;
#pragma unroll
  for (int i = 0; i < 4; ++i)
#pragma unroll
    for (int r = 0; r < 4; ++r) {
      int row = m0 + wm * 64 + i * 16 + lg * 4 + r;
      if (row < M) {
#pragma unroll
        for (int j = 0; j < 4; ++j) {
          int col = n0 + wn * 64 + j * 16 + lm;
          float v = acc[i][j][r];
          if (MODE == 2) v = fmaxf(v + bv[j], 0.f);
          if (OUTK == 1) {
            Ch[(long)t * strideC + (long)row * ldC + col] = f2h(v);
          } else {
            Cf[(long)t * strideC + colOff + (long)row * ldC + col] = v;
          }
        }
      }
    }
}

// ============================ GAT aggregation (z fp16 in, h fp16 out) ============================
// Fast path (deg<=64): lane j owns edge beg+j; el read ONCE, softmax weights kept in
// registers and broadcast via __shfl in the weighted pass. Fallback: 3-pass (deg>64).
__launch_bounds__(256)
__global__ void gat_agg_kernel(const u16* __restrict__ z, const float* __restrict__ el,
                               const float* __restrict__ er, const int* __restrict__ row_ptr,
                               const int* __restrict__ srcs, const float* __restrict__ bias,
                               u16* __restrict__ Hh) {
  int t = blockIdx.y;
  int wv = threadIdx.x >> 6, lane = threadIdx.x & 63;
  int dst = blockIdx.x * 4 + wv;
  if (dst >= N_NODES) return;
  const int* rp = row_ptr + t * (N_NODES + 1);
  int beg = rp[dst], end = rp[dst + 1];
  int deg = end - beg;
  const float* elt = el + (long)t * N_NODES * 4;
  const u16* zt  = z + (long)t * N_NODES * HIDDEN;
  const int* st = srcs + (long)t * NEDGE;
  float4 erd = *(const float4*)(er + (long)t * N_NODES * 4 + ((long)dst << 2));
  int hl = lane >> 4;
  float a0 = 0, a1 = 0, a2 = 0, a3 = 0;
  float inv;

  if (deg <= 64) {
    int s_r = 0;
    float p0 = -INFINITY, p1 = -INFINITY, p2 = -INFINITY, p3 = -INFINITY;
    if (lane < deg) {
      s_r = st[beg + lane];
      float4 ev = *(const float4*)(elt + ((unsigned)s_r << 2));
      p0 = lrelu(ev.x + erd.x);
      p1 = lrelu(ev.y + erd.y);
      p2 = lrelu(ev.z + erd.z);
      p3 = lrelu(ev.w + erd.w);
    }
    float m0 = p0, m1 = p1, m2 = p2, m3 = p3;
#pragma unroll
    for (int off = 32; off; off >>= 1) {
      m0 = fmaxf(m0, __shfl_xor(m0, off));
      m1 = fmaxf(m1, __shfl_xor(m1, off));
      m2 = fmaxf(m2, __shfl_xor(m2, off));
      m3 = fmaxf(m3, __shfl_xor(m3, off));
    }
    p0 = (lane < deg) ? __expf(p0 - m0) : 0.f;
    p1 = (lane < deg) ? __expf(p1 - m1) : 0.f;
    p2 = (lane < deg) ? __expf(p2 - m2) : 0.f;
    p3 = (lane < deg) ? __expf(p3 - m3) : 0.f;
    float d0 = p0, d1 = p1, d2 = p2, d3 = p3;
#pragma unroll
    for (int off = 32; off; off >>= 1) {
      d0 += __shfl_xor(d0, off);
      d1 += __shfl_xor(d1, off);
      d2 += __shfl_xor(d2, off);
      d3 += __shfl_xor(d3, off);
    }
    float dh = (hl == 0) ? d0 : (hl == 1) ? d1 : (hl == 2) ? d2 : d3;
    inv = 1.0f / fmaxf(dh, 1e-9f);
    for (int j = 0; j < deg; ++j) {
      unsigned s = (unsigned)__shfl(s_r, j);
      float w0 = __shfl(p0, j), w1 = __shfl(p1, j);
      float w2 = __shfl(p2, j), w3 = __shfl(p3, j);
      float w = ((hl == 0) ? w0 : (hl == 1) ? w1 : (hl == 2) ? w2 : w3) * inv;
      uint2 zp = *(const uint2*)(zt + (s << 8) + (lane << 2));
      float2 f0 = __half22float2(*(__half2*)&zp.x);
      float2 f1 = __half22float2(*(__half2*)&zp.y);
      a0 = fmaf(w, f0.x, a0);
      a1 = fmaf(w, f0.y, a1);
      a2 = fmaf(w, f1.x, a2);
      a3 = fmaf(w, f1.y, a3);
    }
  } else {
    // -------- fallback: 3-pass --------
    float m0 = -INFINITY, m1 = -INFINITY, m2 = -INFINITY, m3 = -INFINITY;
    for (int j = beg + lane; j < end; j += 64) {
      unsigned s = (unsigned)st[j];
      float4 ev = *(const float4*)(elt + (s << 2));
      m0 = fmaxf(m0, lrelu(ev.x + erd.x));
      m1 = fmaxf(m1, lrelu(ev.y + erd.y));
      m2 = fmaxf(m2, lrelu(ev.z + erd.z));
      m3 = fmaxf(m3, lrelu(ev.w + erd.w));
    }
#pragma unroll
    for (int off = 32; off; off >>= 1) {
      m0 = fmaxf(m0, __shfl_xor(m0, off));
      m1 = fmaxf(m1, __shfl_xor(m1, off));
      m2 = fmaxf(m2, __shfl_xor(m2, off));
      m3 = fmaxf(m3, __shfl_xor(m3, off));
    }
    float d0 = 0, d1 = 0, d2 = 0, d3 = 0;
    for (int j = beg + lane; j < end; j += 64) {
      unsigned s = (unsigned)st[j];
      float4 ev = *(const float4*)(elt + (s << 2));
      d0 += __expf(lrelu(ev.x + erd.x) - m0);
      d1 += __expf(lrelu(ev.y + erd.y) - m1);
      d2 += __expf(lrelu(ev.z + erd.z) - m2);
      d3 += __expf(lrelu(ev.w + erd.w) - m3);
    }
#pragma unroll
    for (int off = 32; off; off >>= 1) {
      d0 += __shfl_xor(d0, off);
      d1 += __shfl_xor(d1, off);
      d2 += __shfl_xor(d2, off);
      d3 += __shfl_xor(d3, off);
    }
    float mh  = (hl == 0) ? m0 : (hl == 1) ? m1 : (hl == 2) ? m2 : m3;
    float dh  = (hl == 0) ? d0 : (hl == 1) ? d1 : (hl == 2) ? d2 : d3;
    float erh = (hl == 0) ? erd.x : (hl == 1) ? erd.y : (hl == 2) ? erd.z : erd.w;
    inv = 1.0f / fmaxf(dh, 1e-9f);
    for (int j = beg; j < end; ++j) {
      unsigned s = (unsigned)st[j];
      float eh = lrelu(elt[(s << 2) + hl] + erh);
      float w = __expf(eh - mh) * inv;
      uint2 zp = *(const uint2*)(zt + (s << 8) + (lane << 2));
      float2 f0 = __half22float2(*(__half2*)&zp.x);
      float2 f1 = __half22float2(*(__half2*)&zp.y);
      a0 = fmaf(w, f0.x, a0);
      a1 = fmaf(w, f0.y, a1);
      a2 = fmaf(w, f1.x, a2);
      a3 = fmaf(w, f1.y, a3);
    }
  }

  float4 bv = *(const float4*)(bias + t * HIDDEN + lane * 4);
  ushort4 o;
  o.x = f2h(fmaxf(a0 + bv.x, 0.f));
  o.y = f2h(fmaxf(a1 + bv.y, 0.f));
  o.z = f2h(fmaxf(a2 + bv.z, 0.f));
  o.w = f2h(fmaxf(a3 + bv.w, 0.f));
  long ob = (long)t * N_NODES * HIDDEN + (long)dst * HIDDEN + lane * 4;
  *(ushort4*)(Hh + ob) = o;
}

// ============================ GIN aggregation on P (fp16 in, fp32 out) ============================
// y = (1+eps)*P[dst] + sum_{src} P[src] + b1
__launch_bounds__(256)
__global__ void gin_agg_kernel(const u16* __restrict__ P, const int* __restrict__ row_ptr,
                               const int* __restrict__ srcs, const float* __restrict__ epsArr,
                               const float* __restrict__ b1, float* __restrict__ y) {
  int t = blockIdx.y;
  int wv = threadIdx.x >> 6, lane = threadIdx.x & 63;
  int dst = blockIdx.x * 4 + wv;
  if (dst >= N_NODES) return;
  const int* rp = row_ptr + t * (N_NODES + 1);
  int beg = rp[dst], end = rp[dst + 1];
  const u16* Pt = P + (long)t * N_NODES * HIDDEN;
  const int* st = srcs + (long)t * NEDGE;
  float ep = 1.0f + epsArr[t];
  float a0 = 0, a1 = 0, a2 = 0, a3 = 0;
  for (int j = beg; j < end; ++j) {
    unsigned s = (unsigned)st[j];
    uint2 pp = *(const uint2*)(Pt + (s << 8) + (lane << 2));
    float2 f0 = __half22float2(*(__half2*)&pp.x);
    float2 f1 = __half22float2(*(__half2*)&pp.y);
    a0 += f0.x; a1 += f0.y; a2 += f1.x; a3 += f1.y;
  }
  uint2 sp = *(const uint2*)(Pt + ((unsigned)dst << 8) + (lane << 2));
  float2 s0 = __half22float2(*(__half2*)&sp.x);
  float2 s1 = __half22float2(*(__half2*)&sp.y);
  float4 bb = *(const float4*)(b1 + t * HIDDEN + lane * 4);
  float4 o;
  o.x = fmaf(ep, s0.x, a0) + bb.x;
  o.y = fmaf(ep, s0.y, a1) + bb.y;
  o.z = fmaf(ep, s1.x, a2) + bb.z;
  o.w = fmaf(ep, s1.y, a3) + bb.w;
  *(float4*)(y + (long)t * N_NODES * HIDDEN + (long)dst * HIDDEN + lane * 4) = o;
}

// ============================ BN stats (two-level, no atomics) ============================
__launch_bounds__(256)
__global__ void stats_kernel(const float* __restrict__ y, long strideY,
                             float* __restrict__ partials) {  // [T][SNB][512]
  const int t = blockIdx.y, blk = blockIdx.x;
  const int tid = threadIdx.x;
  const int col4 = (tid & 63) * 4;
  const int rsub = tid >> 6;
  const int chunk = (N_NODES + SNB - 1) / SNB;
  const int r0 = blk * chunk;
  const int rend = min(r0 + chunk, N_NODES);
  const float* yt = y + (long)t * strideY;
  float s[4] = {0.f, 0.f, 0.f, 0.f}, s2[4] = {0.f, 0.f, 0.f, 0.f};
  for (int r = r0 + rsub; r < rend; r += 4) {
    float4 v = *(const float4*)(yt + (long)r * HIDDEN + col4);
    s[0] += v.x; s2[0] = fmaf(v.x, v.x, s2[0]);
    s[1] += v.y; s2[1] = fmaf(v.y, v.y, s2[1]);
    s[2] += v.z; s2[2] = fmaf(v.z, v.z, s2[2]);
    s[3] += v.w; s2[3] = fmaf(v.w, v.w, s2[3]);
  }
  __shared__ float ls[4][512];
#pragma unroll
  for (int e = 0; e < 4; ++e) {
    ls[rsub][col4 + e] = s[e];
    ls[rsub][256 + col4 + e] = s2[e];
  }
  __syncthreads();
  for (int i = tid; i < 512; i += 256) {
    float v = ls[0][i] + ls[1][i] + ls[2][i] + ls[3][i];
    partials[((long)t * SNB + blk) * 512 + i] = v;
  }
}

__global__ void bn_finalize_kernel(const float* __restrict__ partials,
                                   const float* __restrict__ g1, const float* __restrict__ be1,
                                   float* __restrict__ scale, float* __restrict__ shift) {
  int i = threadIdx.x + blockIdx.x * blockDim.x;
  if (i >= NTYPE * HIDDEN) return;
  int t = i / HIDDEN, c = i % HIDDEN;
  float s = 0.f, s2 = 0.f;
  for (int b = 0; b < SNB; ++b) {
    s  += partials[((long)t * SNB + b) * 512 + c];
    s2 += partials[((long)t * SNB + b) * 512 + 256 + c];
  }
  float mu  = s * (1.0f / N_NODES);
  float ms  = s2 * (1.0f / N_NODES);
  float var = ms - mu * mu;
  float sc = g1[i] * rsqrtf(var + 1e-5f);
  scale[i] = sc;
  shift[i] = be1[i] - mu * sc;
}

// ============================ launch ============================
extern "C" void kernel_launch(void* const* d_in, const int* in_sizes, int n_in,
                              void* d_out, int out_size, void* d_ws, size_t ws_size,
                              hipStream_t stream) {
  const float* feats   = (const float*)d_in[0];
  const int* src0      = (const int*)d_in[1];
  const int* dst0      = (const int*)d_in[2];
  const int* src1      = (const int*)d_in[3];
  const int* dst1      = (const int*)d_in[4];
  const float* gat0_W  = (const float*)d_in[5];
  const float* gat0_al = (const float*)d_in[6];
  const float* gat0_ar = (const float*)d_in[7];
  const float* gat0_b  = (const float*)d_in[8];
  const float* gat1_W  = (const float*)d_in[9];
  const float* gat1_al = (const float*)d_in[10];
  const float* gat1_ar = (const float*)d_in[11];
  const float* gat1_b  = (const float*)d_in[12];
  const float* gin0_eps = (const float*)d_in[13];
  const float* gin0_W1  = (const float*)d_in[14];
  const float* gin0_b1  = (const float*)d_in[15];
  const float* gin0_g1  = (const float*)d_in[16];
  const float* gin0_be1 = (const float*)d_in[17];
  const float* gin0_W2  = (const float*)d_in[18];
  const float* gin0_b2  = (const float*)d_in[19];
  const float* gin1_eps = (const float*)d_in[20];
  const float* gin1_W1  = (const float*)d_in[21];
  const float* gin1_b1  = (const float*)d_in[22];
  const float* gin1_g1  = (const float*)d_in[23];
  const float* gin1_be1 = (const float*)d_in[24];
  const float* gin1_W2  = (const float*)d_in[25];
  const float* gin1_b2  = (const float*)d_in[26];
  float* out = (float*)d_out;

  char* p = (char*)d_ws;
  size_t off = 0;
  auto take = [&](size_t bytes) -> void* {
    void* r = p + off;
    off = (off + bytes + 255) & ~(size_t)255;
    return r;
  };
  float* bufA = (float*)take((size_t)NTYPE * N_NODES * HIDDEN * 4);  // y (fp32)
  u16*   bufZ = (u16*)take((size_t)NTYPE * N_NODES * HIDDEN * 2);    // z / P (fp16)
  u16*   bufH = (u16*)take((size_t)NTYPE * N_NODES * HIDDEN * 2);    // h (fp16)
  u16*   fh   = (u16*)take((size_t)N_NODES * F_IN * 2);
  float* el   = (float*)take((size_t)NTYPE * N_NODES * 4 * 4);
  float* er   = (float*)take((size_t)NTYPE * N_NODES * 4 * 4);
  int* counts  = (int*)take((size_t)NTYPE * N_NODES * 4);
  int* row_ptr = (int*)take((size_t)NTYPE * (N_NODES + 1) * 4);
  int* cursor  = (int*)take((size_t)NTYPE * N_NODES * 4);
  int* srcs    = (int*)take((size_t)NTYPE * NEDGE * 4);
  float* bn_part  = (float*)take((size_t)NTYPE * SNB * 512 * 4);
  float* bn_scale = (float*)take((size_t)NTYPE * HIDDEN * 4);
  float* bn_shift = (float*)take((size_t)NTYPE * HIDDEN * 4);
  u16* w_g0   = (u16*)take((size_t)NTYPE * 256 * 128 * 2);
  u16* w_g1   = (u16*)take((size_t)NTYPE * 256 * 256 * 2);
  u16* w_i0w1 = (u16*)take((size_t)NTYPE * 256 * 384 * 2);
  u16* w_i0w2 = (u16*)take((size_t)NTYPE * 256 * 256 * 2);
  u16* w_i1w1 = (u16*)take((size_t)NTYPE * 256 * 256 * 2);
  u16* w_i1w2 = (u16*)take((size_t)NTYPE * 256 * 256 * 2);
  (void)ws_size; (void)in_sizes; (void)n_in; (void)out_size;

  const dim3 blk(256);
  const int egrid = (NEDGE + 255) / 256;
  const dim3 ggrid((N_NODES + 127) / 128, 2, NTYPE);
  const dim3 agrid((N_NODES + 3) / 4, NTYPE);
  const dim3 sgrid(SNB, NTYPE);
  const long sN256 = (long)N_NODES * HIDDEN;

  // ---- prep ----
  prep_feats_kernel<<<(N_NODES * F_IN / 4 + 255) / 256, blk, 0, stream>>>(feats, fh);
  prep_b_kernel<<<dim3(2, 4, NTYPE), blk, 0, stream>>>(gat0_W, w_g0, 128);
  prep_b_kernel<<<dim3(4, 4, NTYPE), blk, 0, stream>>>(gat1_W, w_g1, 256);
  prep_b_kernel<<<dim3(6, 4, NTYPE), blk, 0, stream>>>(gin0_W1, w_i0w1, 384);
  prep_b_kernel<<<dim3(4, 4, NTYPE), blk, 0, stream>>>(gin0_W2, w_i0w2, 256);
  prep_b_kernel<<<dim3(4, 4, NTYPE), blk, 0, stream>>>(gin1_W1, w_i1w1, 256);
  prep_b_kernel<<<dim3(4, 4, NTYPE), blk, 0, stream>>>(gin1_W2, w_i1w2, 256);

  // ---- CSR build ----
  hipMemsetAsync(counts, 0, (size_t)NTYPE * N_NODES * 4, stream);
  hist_kernel<<<dim3(egrid, NTYPE), blk, 0, stream>>>(dst0, dst1, counts);
  scan_kernel<<<NTYPE, 1024, 0, stream>>>(counts, row_ptr, cursor);
  scatter_kernel<<<dim3(egrid, NTYPE), blk, 0, stream>>>(src0, dst0, src1, dst1, cursor, srcs);

  // ---- GAT layer 0 (K=128) ----
  gemm_mfma<0, true, 1><<<ggrid, blk, 0, stream>>>(nullptr,
      fh, 0L, F_IN, F_IN, nullptr, 0L, 0, 0L, F_IN,
      w_g0, nullptr, nullptr, bufZ, sN256, HIDDEN, 0,
      gat0_al, gat0_ar, el, er, nullptr, nullptr, N_NODES);
  gat_agg_kernel<<<agrid, blk, 0, stream>>>(bufZ, el, er, row_ptr, srcs, gat0_b, bufH);

  // ---- GAT layer 1 (K=256) ----
  gemm_mfma<0, true, 1><<<ggrid, blk, 0, stream>>>(nullptr,
      bufH, sN256, HIDDEN, HIDDEN, nullptr, 0L, 0, 0L, HIDDEN,
      w_g1, nullptr, nullptr, bufZ, sN256, HIDDEN, 0,
      gat1_al, gat1_ar, el, er, nullptr, nullptr, N_NODES);
  gat_agg_kernel<<<agrid, blk, 0, stream>>>(bufZ, el, er, row_ptr, srcs, gat1_b, bufH);

  // ---- GIN layer 0: P = [h | feats] @ W1 (K=384), then aggregate P ----
  gemm_mfma<1, true, 1><<<ggrid, blk, 0, stream>>>(nullptr,
      bufH, sN256, HIDDEN, HIDDEN, fh, 0L, F_IN, 0L, HIDDEN + F_IN,
      w_i0w1, nullptr, nullptr, bufZ, sN256, HIDDEN, 0,
      nullptr, nullptr, nullptr, nullptr, nullptr, nullptr, N_NODES);
  gin_agg_kernel<<<agrid, blk, 0, stream>>>(bufZ, row_ptr, srcs, gin0_eps, gin0_b1, bufA);
  stats_kernel<<<sgrid, blk, 0, stream>>>(bufA, sN256, bn_part);
  bn_finalize_kernel<<<1, NTYPE * HIDDEN, 0, stream>>>(bn_part, gin0_g1, gin0_be1, bn_scale, bn_shift);
  gemm_mfma<2, false, 1><<<ggrid, blk, 0, stream>>>(bufA,
      nullptr, 0L, HIDDEN, HIDDEN, nullptr, 0L, 0, sN256, HIDDEN,
      w_i0w2, gin0_b2, nullptr, bufH, sN256, HIDDEN, 0,
      nullptr, nullptr, nullptr, nullptr, bn_scale, bn_shift, N_NODES);

  // ---- GIN layer 1 (K=256) ----
  gemm_mfma<1, true, 1><<<ggrid, blk, 0, stream>>>(nullptr,
      bufH, sN256, HIDDEN, HIDDEN, nullptr, 0L, 0, 0L, HIDDEN,
      w_i1w1, nullptr, nullptr, bufZ, sN256, HIDDEN, 0,
      nullptr, nullptr, nullptr, nullptr, nullptr, nullptr, N_NODES);
  gin_agg_kernel<<<agrid, blk, 0, stream>>>(bufZ, row_ptr, srcs, gin1_eps, gin1_b1, bufA);
  stats_kernel<<<sgrid, blk, 0, stream>>>(bufA, sN256, bn_part);
  bn_finalize_kernel<<<1, NTYPE * HIDDEN, 0, stream>>>(bn_part, gin1_g1, gin1_be1, bn_scale, bn_shift);
  gemm_mfma<2, false, 0><<<ggrid, blk, 0, stream>>>(bufA,
      nullptr, 0L, HIDDEN, HIDDEN, nullptr, 0L, 0, sN256, HIDDEN,
      w_i1w2, gin1_b2, out, nullptr, 0L, NTYPE * HIDDEN, HIDDEN,
      nullptr, nullptr, nullptr, nullptr, bn_scale, bn_shift, N_NODES);
}